// Round 6
// baseline (618.772 us; speedup 1.0000x reference)
//
#include <hip/hip_runtime.h>
#include <hip/hip_bf16.h>
#include <cstdint>
#include <cstddef>

// TT-dense: y = relu(x @ M + b)
// x: [4096,4096] f32, M: TT(cores r=1,16,16,16,1, dims 8^4 x 8^4), out f32.
//
// Route: materialize M^T in bf16 (~0.67 GFLOP), convert x to bf16, one
// 4096^3 bf16 MFMA GEMM with fused bias+relu.
// R2: swizzle killed bank conflicts at BK=32; R3: ping-pong dbuf regressed
//     (dynamic LDS indexing -> VALU bound); R4: BK=64 -> 165us GEMM but
//     half-rate swizzle brought conflicts back; R5: full-rate swizzle ->
//     0 conflicts, 160us GEMM, BUT fused pre-work regressed (4096 blocks
//     x 268M scalar gathers from cores) -> reverted to split pre-work.
// R6: LDS-FREE GEMM. A and Mt are both K-contiguous; a 16x16x32 fragment is
//     16 contiguous bytes/lane -> direct global_load_dwordx4 fragments.
//     No staging, no ds_read, no barriers in the K-loop; loads stay in
//     flight across iterations (compiler vmcnt(N) pipelining). LDS pipe
//     (~1024 cyc/block-iter) eliminated; L1/L2 absorb the 2x wave-level
//     operand duplication.

#define GM 4096
#define GN 4096
#define GK 4096

typedef __attribute__((ext_vector_type(8))) short short8_t;
typedef __attribute__((ext_vector_type(4))) float float4_t;

__device__ __forceinline__ unsigned short f2bf(float f) {
  union { float f; uint32_t u; } v; v.f = f;
  uint32_t u = v.u;
  uint32_t r = (u + 0x7fffu + ((u >> 16) & 1u)) >> 16;  // RNE
  return (unsigned short)r;
}

// ---------------------------------------------------------------------------
// Kernel 1 (merged): blocks [0,512): merge core pairs -> G01, G23t.
//                    blocks [512,8704): x f32 -> bf16.
// G01[a01][b01][r2] = sum_r1 core0[0,a0,b0,r1] * core1[r1,a1,b1,r2]
// G23t[r2][b23][a23] = sum_r3 core2[r2,a2,b2,r3] * core3[r3,a3,b3,0]
// ---------------------------------------------------------------------------
__global__ __launch_bounds__(256) void prep_convert(
    const float* __restrict__ c0, const float* __restrict__ c1,
    const float* __restrict__ c2, const float* __restrict__ c3,
    float* __restrict__ G01, float* __restrict__ G23t,
    const float* __restrict__ x, unsigned short* __restrict__ xb) {
  int bid = blockIdx.x;
  if (bid < 512) {
    int idx = bid * 256 + threadIdx.x;  // 0..131071
    if (idx < 65536) {
      int r2 = idx & 15;
      int b01 = (idx >> 4) & 63;
      int a01 = idx >> 10;
      int a0 = a01 >> 3, a1 = a01 & 7, b0 = b01 >> 3, b1 = b01 & 7;
      float s = 0.f;
#pragma unroll
      for (int r1 = 0; r1 < 16; ++r1)
        s += c0[(a0 * 8 + b0) * 16 + r1] * c1[((r1 * 8 + a1) * 8 + b1) * 16 + r2];
      G01[idx] = s;
    } else {
      int t = idx - 65536;  // t = r2*4096 + b23*64 + a23
      int a23 = t & 63;
      int b23 = (t >> 6) & 63;
      int r2 = t >> 12;
      int a2 = a23 >> 3, a3 = a23 & 7, b2 = b23 >> 3, b3 = b23 & 7;
      float s = 0.f;
#pragma unroll
      for (int r3 = 0; r3 < 16; ++r3)
        s += c2[((r2 * 8 + a2) * 8 + b2) * 16 + r3] * c3[(r3 * 8 + a3) * 8 + b3];
      G23t[t] = s;
    }
  } else {
    int i = ((bid - 512) * 256 + threadIdx.x) * 8;
    float4_t a = *(const float4_t*)(x + i);
    float4_t b = *(const float4_t*)(x + i + 4);
    short8_t o;
    o[0] = (short)f2bf(a[0]); o[1] = (short)f2bf(a[1]);
    o[2] = (short)f2bf(a[2]); o[3] = (short)f2bf(a[3]);
    o[4] = (short)f2bf(b[0]); o[5] = (short)f2bf(b[1]);
    o[6] = (short)f2bf(b[2]); o[7] = (short)f2bf(b[3]);
    *(short8_t*)(xb + i) = o;
  }
}

// ---------------------------------------------------------------------------
// Kernel 2: Mt[n][k] bf16, n = b01*64+b23, k = a01*64+a23.
// Mt[n][k] = sum_r2 G01[a01][b01][r2] * G23t[r2][b23][a23]
// Per-thread contiguous 16-elem span: float4 loads, short8 stores.
// G23t L2-resident (256 KB).
// ---------------------------------------------------------------------------
__global__ __launch_bounds__(256) void build_mt(
    const float* __restrict__ G01, const float* __restrict__ G23t,
    unsigned short* __restrict__ Mt) {
  int a01 = blockIdx.x >> 4;
  int g = blockIdx.x & 15;  // b01 = g*4 + j
  int tid = threadIdx.x;

  float acc[4][16];
#pragma unroll
  for (int j = 0; j < 4; ++j)
#pragma unroll
    for (int i = 0; i < 16; ++i) acc[j][i] = 0.f;

  for (int r2 = 0; r2 < 16; ++r2) {
    float gv[4];
#pragma unroll
    for (int j = 0; j < 4; ++j)
      gv[j] = G01[(a01 * 64 + g * 4 + j) * 16 + r2];  // block-uniform
    const float* src = G23t + r2 * 4096 + tid * 16;   // 64B contiguous/lane
    float4_t v0 = *(const float4_t*)(src);
    float4_t v1 = *(const float4_t*)(src + 4);
    float4_t v2 = *(const float4_t*)(src + 8);
    float4_t v3 = *(const float4_t*)(src + 12);
#pragma unroll
    for (int j = 0; j < 4; ++j) {
#pragma unroll
      for (int l = 0; l < 4; ++l) {
        acc[j][l]      += gv[j] * v0[l];
        acc[j][4 + l]  += gv[j] * v1[l];
        acc[j][8 + l]  += gv[j] * v2[l];
        acc[j][12 + l] += gv[j] * v3[l];
      }
    }
  }

  int b23 = tid >> 2;
  int a23base = (tid & 3) * 16;
#pragma unroll
  for (int j = 0; j < 4; ++j) {
    short8_t o0, o1;
#pragma unroll
    for (int i = 0; i < 8; ++i) {
      o0[i] = (short)f2bf(acc[j][i]);
      o1[i] = (short)f2bf(acc[j][8 + i]);
    }
    size_t base = (size_t)((g * 4 + j) * 64 + b23) * GK + a01 * 64 + a23base;
    *(short8_t*)(Mt + base) = o0;
    *(short8_t*)(Mt + base + 8) = o1;
  }
}

// ---------------------------------------------------------------------------
// Kernel 3: C = relu(A @ Bt^T + bias). A:[M][K] bf16, Bt:[N][K] bf16.
// LDS-free register GEMM: 128x128 block tile, 4 waves (2x2, 64x64 each,
// 4x4 MFMA tiles), 16x16x32 bf16 MFMA. Fragments loaded straight from
// global as dwordx4 (A/Bt are K-contiguous; lane's fragment = 16
// contiguous bytes at [row][k + half*8]). No LDS, no __syncthreads:
// loads pipeline across K-iterations via compiler vmcnt(N).
//
// XCD swizzle: all 1024 blocks co-resident (4/CU); each XCD gets an 8x16
// tile of the 32x32 block grid for L2 locality of A/Bt panels.
// ---------------------------------------------------------------------------
__global__ __launch_bounds__(256) void gemm_bias_relu(
    const unsigned short* __restrict__ A, const unsigned short* __restrict__ Bt,
    const float* __restrict__ bias, float* __restrict__ C) {
  int tid = threadIdx.x;
  int bswz = blockIdx.x;
  int xcd = bswz & 7, li = bswz >> 3;
  int row0 = (((xcd >> 1) * 8) + (li >> 4)) * 128;  // 32 row-blocks
  int col0 = (((xcd & 1) * 16) + (li & 15)) * 128;  // 32 col-blocks
  int wave = tid >> 6, lane = tid & 63;
  int wr = (wave >> 1) * 64, wc = (wave & 1) * 64;
  int half = lane >> 4, mrow = lane & 15;

  float4_t acc[4][4];
#pragma unroll
  for (int i = 0; i < 4; ++i)
#pragma unroll
    for (int j = 0; j < 4; ++j) acc[i][j] = (float4_t){0.f, 0.f, 0.f, 0.f};

  // Per-lane fragment base pointers (16B chunks). A-frag for tile i at
  // k-base kb: A[row0+wr+i*16+mrow][kb + half*8 .. +8] — one short8.
  const short8_t* Ap[4];
  const short8_t* Bp[4];
#pragma unroll
  for (int i = 0; i < 4; ++i) {
    Ap[i] = (const short8_t*)(A + (size_t)(row0 + wr + i * 16 + mrow) * GK +
                              half * 8);
    Bp[i] = (const short8_t*)(Bt + (size_t)(col0 + wc + i * 16 + mrow) * GK +
                              half * 8);
  }

  // K-loop: 64 elems (2 MFMA k-steps) per iteration. Index unit = 8 shorts.
  for (int k8 = 0; k8 < GK / 8; k8 += 8) {
    short8_t af[2][4], bfr[2][4];
#pragma unroll
    for (int ks = 0; ks < 2; ++ks)
#pragma unroll
      for (int i = 0; i < 4; ++i) {
        af[ks][i] = Ap[i][k8 + ks * 4];
        bfr[ks][i] = Bp[i][k8 + ks * 4];
      }
#pragma unroll
    for (int ks = 0; ks < 2; ++ks)
#pragma unroll
      for (int i = 0; i < 4; ++i)
#pragma unroll
        for (int j = 0; j < 4; ++j)
          acc[i][j] = __builtin_amdgcn_mfma_f32_16x16x32_bf16(
              af[ks][i], bfr[ks][j], acc[i][j], 0, 0, 0);
  }

  // Epilogue: C/D layout col=lane&15, row=(lane>>4)*4+reg. Fuse bias+relu.
#pragma unroll
  for (int j = 0; j < 4; ++j) {
    int col = col0 + wc + j * 16 + mrow;
    float bcol = bias[col];
#pragma unroll
    for (int i = 0; i < 4; ++i) {
#pragma unroll
      for (int r = 0; r < 4; ++r) {
        int row = row0 + wr + i * 16 + half * 4 + r;
        float v = acc[i][j][r] + bcol;
        C[(size_t)row * GN + col] = v > 0.f ? v : 0.f;
      }
    }
  }
}

// ---------------------------------------------------------------------------
extern "C" void kernel_launch(void* const* d_in, const int* in_sizes, int n_in,
                              void* d_out, int out_size, void* d_ws, size_t ws_size,
                              hipStream_t stream) {
  const float* x  = (const float*)d_in[0];
  const float* c0 = (const float*)d_in[1];
  const float* c1 = (const float*)d_in[2];
  const float* c2 = (const float*)d_in[3];
  const float* c3 = (const float*)d_in[4];
  const float* b  = (const float*)d_in[5];
  float* out = (float*)d_out;

  // Workspace layout: [xb 32MB][Mt 32MB][G01 256KB][G23t 256KB]
  unsigned short* xb = (unsigned short*)d_ws;
  unsigned short* Mt = (unsigned short*)((char*)d_ws + (32u << 20));
  float* G01 = (float*)((char*)d_ws + (64u << 20));
  float* G23t = G01 + 65536;

  prep_convert<<<512 + (GM * GK) / (256 * 8), 256, 0, stream>>>(
      c0, c1, c2, c3, G01, G23t, x, xb);
  build_mt<<<1024, 256, 0, stream>>>(G01, G23t, Mt);
  gemm_bias_relu<<<(GM / 128) * (GN / 128), 256, 0, stream>>>(xb, Mt, b, out);
}

// Round 7
// 268.699 us; speedup vs baseline: 2.3028x; 2.3028x over previous
//
#include <hip/hip_runtime.h>
#include <hip/hip_bf16.h>
#include <cstdint>
#include <cstddef>

// TT-dense: y = relu(x @ M + b)
// x: [4096,4096] f32, M: TT(cores r=1,16,16,16,1, dims 8^4 x 8^4), out f32.
//
// Route: materialize M^T in bf16 (~0.67 GFLOP), convert x to bf16, one
// 4096^3 bf16 MFMA GEMM with fused bias+relu.
// History: R2 swizzle kills conflicts @BK=32; R3 ping-pong dbuf regressed
//   (dynamic LDS idx -> VALU bound); R4 BK=64 -> 165us but half-rate swizzle
//   re-introduced conflicts; R5 full-rate swizzle -> 0 conflicts, 160us GEMM
//   (fused pre-work regressed -> split); R6 LDS-free GEMM regressed hard
//   (513us: 16-row strided fragment loads splinter into 16+ transactions).
// R7: best-known combo + pre-work pipelining: tiny prep dispatch first, then
//   build_mt and convert fused in one dispatch (mutually independent), then
//   the R5 GEMM (full-rate swizzle, XCD tiling).

#define GM 4096
#define GN 4096
#define GK 4096

typedef __attribute__((ext_vector_type(8))) short short8_t;
typedef __attribute__((ext_vector_type(4))) float float4_t;

__device__ __forceinline__ unsigned short f2bf(float f) {
  union { float f; uint32_t u; } v; v.f = f;
  uint32_t u = v.u;
  uint32_t r = (u + 0x7fffu + ((u >> 16) & 1u)) >> 16;  // RNE
  return (unsigned short)r;
}

// ---------------------------------------------------------------------------
// Kernel 1 (512 blocks, ~4us): merge core pairs.
// G01[a01][b01][r2] = sum_r1 core0[0,a0,b0,r1] * core1[r1,a1,b1,r2]
// G23t[r2][b23][a23] = sum_r3 core2[r2,a2,b2,r3] * core3[r3,a3,b3,0]
// ---------------------------------------------------------------------------
__global__ __launch_bounds__(256) void prep_kernel(
    const float* __restrict__ c0, const float* __restrict__ c1,
    const float* __restrict__ c2, const float* __restrict__ c3,
    float* __restrict__ G01, float* __restrict__ G23t) {
  int idx = blockIdx.x * 256 + threadIdx.x;  // 0..131071
  if (idx < 65536) {
    int r2 = idx & 15;
    int b01 = (idx >> 4) & 63;
    int a01 = idx >> 10;
    int a0 = a01 >> 3, a1 = a01 & 7, b0 = b01 >> 3, b1 = b01 & 7;
    float s = 0.f;
#pragma unroll
    for (int r1 = 0; r1 < 16; ++r1)
      s += c0[(a0 * 8 + b0) * 16 + r1] * c1[((r1 * 8 + a1) * 8 + b1) * 16 + r2];
    G01[idx] = s;
  } else {
    int t = idx - 65536;  // t = r2*4096 + b23*64 + a23
    int a23 = t & 63;
    int b23 = (t >> 6) & 63;
    int r2 = t >> 12;
    int a2 = a23 >> 3, a3 = a23 & 7, b2 = b23 >> 3, b3 = b23 & 7;
    float s = 0.f;
#pragma unroll
    for (int r3 = 0; r3 < 16; ++r3)
      s += c2[((r2 * 8 + a2) * 8 + b2) * 16 + r3] * c3[(r3 * 8 + a3) * 8 + b3];
    G23t[t] = s;
  }
}

// ---------------------------------------------------------------------------
// Kernel 2 (fused, mutually independent halves):
//  blocks [0,1024): Mt[n][k] = sum_r2 G01[a01][b01][r2] * G23t[r2][b23][a23]
//    (n = b01*64+b23, k = a01*64+a23). float4 loads, short8 stores,
//    G23t L2-resident.
//  blocks [1024, 9216): x f32 -> bf16 RNE, 8 elems/thread.
// ---------------------------------------------------------------------------
__global__ __launch_bounds__(256) void mt_convert(
    const float* __restrict__ G01, const float* __restrict__ G23t,
    unsigned short* __restrict__ Mt,
    const float* __restrict__ x, unsigned short* __restrict__ xb) {
  int bid = blockIdx.x;
  int tid = threadIdx.x;
  if (bid < 1024) {
    int a01 = bid >> 4;
    int g = bid & 15;  // b01 = g*4 + j

    float acc[4][16];
#pragma unroll
    for (int j = 0; j < 4; ++j)
#pragma unroll
      for (int i = 0; i < 16; ++i) acc[j][i] = 0.f;

    for (int r2 = 0; r2 < 16; ++r2) {
      float gv[4];
#pragma unroll
      for (int j = 0; j < 4; ++j)
        gv[j] = G01[(a01 * 64 + g * 4 + j) * 16 + r2];  // block-uniform
      const float* src = G23t + r2 * 4096 + tid * 16;   // 64B contiguous/lane
      float4_t v0 = *(const float4_t*)(src);
      float4_t v1 = *(const float4_t*)(src + 4);
      float4_t v2 = *(const float4_t*)(src + 8);
      float4_t v3 = *(const float4_t*)(src + 12);
#pragma unroll
      for (int j = 0; j < 4; ++j) {
#pragma unroll
        for (int l = 0; l < 4; ++l) {
          acc[j][l]      += gv[j] * v0[l];
          acc[j][4 + l]  += gv[j] * v1[l];
          acc[j][8 + l]  += gv[j] * v2[l];
          acc[j][12 + l] += gv[j] * v3[l];
        }
      }
    }

    int b23 = tid >> 2;
    int a23base = (tid & 3) * 16;
#pragma unroll
    for (int j = 0; j < 4; ++j) {
      short8_t o0, o1;
#pragma unroll
      for (int i = 0; i < 8; ++i) {
        o0[i] = (short)f2bf(acc[j][i]);
        o1[i] = (short)f2bf(acc[j][8 + i]);
      }
      size_t base = (size_t)((g * 4 + j) * 64 + b23) * GK + a01 * 64 + a23base;
      *(short8_t*)(Mt + base) = o0;
      *(short8_t*)(Mt + base + 8) = o1;
    }
  } else {
    int i = ((bid - 1024) * 256 + tid) * 8;
    float4_t a = *(const float4_t*)(x + i);
    float4_t b = *(const float4_t*)(x + i + 4);
    short8_t o;
    o[0] = (short)f2bf(a[0]); o[1] = (short)f2bf(a[1]);
    o[2] = (short)f2bf(a[2]); o[3] = (short)f2bf(a[3]);
    o[4] = (short)f2bf(b[0]); o[5] = (short)f2bf(b[1]);
    o[6] = (short)f2bf(b[2]); o[7] = (short)f2bf(b[3]);
    *(short8_t*)(xb + i) = o;
  }
}

// ---------------------------------------------------------------------------
// Kernel 3: C = relu(A @ Bt^T + bias). A:[M][K] bf16, Bt:[N][K] bf16.
// 128x128 tile, BK=64 (32 KB LDS), 4 waves (2x2), global_load_lds width-16
// staging, 16x16x32 bf16 MFMA, single buffer, 2 barriers / 32 MFMA per iter.
//
// LDS chunk swizzle (full-rate): row r (64 bf16 = 8 x 16B chunks) stores
// k-half h at position p = (h + r) & 7. With 128B row stride the bank group
// depends only on p, so 8 consecutive rows at fixed h cover all 8 positions
// -> 0 conflicts (verified R5: SQ_LDS_BANK_CONFLICT = 0). Staging keeps the
// lane-contiguous LDS dest required by global_load_lds and permutes the
// global source k-offset (still fully coalesced per row).
//
// XCD swizzle: all 1024 blocks co-resident (4/CU); each XCD gets an 8x16
// tile of the 32x32 block grid for L2 locality.
// ---------------------------------------------------------------------------
__global__ __launch_bounds__(256) void gemm_bias_relu(
    const unsigned short* __restrict__ A, const unsigned short* __restrict__ Bt,
    const float* __restrict__ bias, float* __restrict__ C) {
  __shared__ __align__(16) unsigned short As[128 * 64];  // 16 KB
  __shared__ __align__(16) unsigned short Bs[128 * 64];  // 16 KB

  int tid = threadIdx.x;
  int bswz = blockIdx.x;
  int xcd = bswz & 7, li = bswz >> 3;
  int row0 = (((xcd >> 1) * 8) + (li >> 4)) * 128;  // 32 row-blocks
  int col0 = (((xcd & 1) * 16) + (li & 15)) * 128;  // 32 col-blocks
  int wave = tid >> 6, lane = tid & 63;
  int wr = (wave >> 1) * 64, wc = (wave & 1) * 64;
  int half = lane >> 4, mrow = lane & 15;

  float4_t acc[4][4];
#pragma unroll
  for (int i = 0; i < 4; ++i)
#pragma unroll
    for (int j = 0; j < 4; ++j) acc[i][j] = (float4_t){0.f, 0.f, 0.f, 0.f};

  // Staging: thread owns chunks c = q*256+tid (q=0..3) per matrix.
  // Chunk c: row r = c>>3, pos p = c&7, source k-half h = (p - r) & 7.
  const unsigned short* Ap[4];
  const unsigned short* Bp[4];
  int cdst[4];
#pragma unroll
  for (int q = 0; q < 4; ++q) {
    int c = q * 256 + tid;
    int r = c >> 3;
    int h = ((c & 7) - r) & 7;
    Ap[q] = A + (size_t)(row0 + r) * GK + h * 8;
    Bp[q] = Bt + (size_t)(col0 + r) * GK + h * 8;
    cdst[q] = c * 8;  // shorts
  }

  // Swizzled fragment offsets (loop-invariant): k-step ks in {0,1};
  // wanted k-half hw = ks*4 + half, read position p = (hw + r) & 7.
  int aoff[2][4], boff[2][4];
#pragma unroll
  for (int ks = 0; ks < 2; ++ks) {
#pragma unroll
    for (int i = 0; i < 4; ++i) {
      int rA = wr + i * 16 + mrow;
      aoff[ks][i] = rA * 64 + ((((ks * 4 + half) + rA) & 7) * 8);
      int rB = wc + i * 16 + mrow;
      boff[ks][i] = rB * 64 + ((((ks * 4 + half) + rB) & 7) * 8);
    }
  }

  for (int k0 = 0; k0 < GK; k0 += 64) {
#pragma unroll
    for (int q = 0; q < 4; ++q) {
      __builtin_amdgcn_global_load_lds(
          (const __attribute__((address_space(1))) void*)(Ap[q] + k0),
          (__attribute__((address_space(3))) void*)(As + cdst[q]), 16, 0, 0);
      __builtin_amdgcn_global_load_lds(
          (const __attribute__((address_space(1))) void*)(Bp[q] + k0),
          (__attribute__((address_space(3))) void*)(Bs + cdst[q]), 16, 0, 0);
    }
    __syncthreads();

#pragma unroll
    for (int ks = 0; ks < 2; ++ks) {
      short8_t af[4], bfr[4];
#pragma unroll
      for (int i = 0; i < 4; ++i) af[i] = *(const short8_t*)&As[aoff[ks][i]];
#pragma unroll
      for (int j = 0; j < 4; ++j) bfr[j] = *(const short8_t*)&Bs[boff[ks][j]];
#pragma unroll
      for (int i = 0; i < 4; ++i)
#pragma unroll
        for (int j = 0; j < 4; ++j)
          acc[i][j] = __builtin_amdgcn_mfma_f32_16x16x32_bf16(af[i], bfr[j],
                                                              acc[i][j], 0, 0, 0);
    }
    __syncthreads();
  }

  // Epilogue: C/D layout col=lane&15, row=(lane>>4)*4+reg. Fuse bias+relu.
#pragma unroll
  for (int j = 0; j < 4; ++j) {
    int col = col0 + wc + j * 16 + mrow;
    float bcol = bias[col];
#pragma unroll
    for (int i = 0; i < 4; ++i) {
#pragma unroll
      for (int r = 0; r < 4; ++r) {
        int row = row0 + wr + i * 16 + half * 4 + r;
        float v = acc[i][j][r] + bcol;
        C[(size_t)row * GN + col] = v > 0.f ? v : 0.f;
      }
    }
  }
}

// ---------------------------------------------------------------------------
extern "C" void kernel_launch(void* const* d_in, const int* in_sizes, int n_in,
                              void* d_out, int out_size, void* d_ws, size_t ws_size,
                              hipStream_t stream) {
  const float* x  = (const float*)d_in[0];
  const float* c0 = (const float*)d_in[1];
  const float* c1 = (const float*)d_in[2];
  const float* c2 = (const float*)d_in[3];
  const float* c3 = (const float*)d_in[4];
  const float* b  = (const float*)d_in[5];
  float* out = (float*)d_out;

  // Workspace layout: [xb 32MB][Mt 32MB][G01 256KB][G23t 256KB]
  unsigned short* xb = (unsigned short*)d_ws;
  unsigned short* Mt = (unsigned short*)((char*)d_ws + (32u << 20));
  float* G01 = (float*)((char*)d_ws + (64u << 20));
  float* G23t = G01 + 65536;

  prep_kernel<<<512, 256, 0, stream>>>(c0, c1, c2, c3, G01, G23t);
  mt_convert<<<1024 + (GM * GK) / (256 * 8), 256, 0, stream>>>(
      G01, G23t, Mt, x, xb);
  gemm_bias_relu<<<(GM / 128) * (GN / 128), 256, 0, stream>>>(xb, Mt, b, out);
}